// Round 11
// baseline (190.032 us; speedup 1.0000x reference)
//
#include <hip/hip_runtime.h>
#include <hip/hip_bf16.h>
#include <stdint.h>

#define S_LEN 2048
#define BATCH 4
#define NH    16
#define DH    64
#define DM    1024
#define MTOT  (BATCH*S_LEN)

typedef short bf16x8 __attribute__((ext_vector_type(8)));
typedef float f32x4 __attribute__((ext_vector_type(4)));
typedef uint32_t u32x4 __attribute__((ext_vector_type(4)));

__device__ __forceinline__ uint16_t f2bf(float f) {
  union { float f; uint32_t i; } c; c.f = f;
  uint32_t r = c.i + 0x7fffu + ((c.i >> 16) & 1u);
  return (uint16_t)(r >> 16);
}
__device__ __forceinline__ float bf2f(uint16_t u) {
  union { uint32_t i; float f; } c; c.i = ((uint32_t)u) << 16; return c.f;
}

__device__ __forceinline__ uint32_t cvt_pk_bf16(float a, float b) {
  uint32_t r;
  asm("v_cvt_pk_bf16_f32 %0, %1, %2" : "=v"(r) : "v"(a), "v"(b));
  return r;
}

__device__ __forceinline__ void async_copy16(void* lds, const void* g) {
  __builtin_amdgcn_global_load_lds(
      (const __attribute__((address_space(1))) void*)g,
      (__attribute__((address_space(3))) void*)lds, 16, 0, 0);
}

// ---------------- fp32 -> bf16 convert ----------------
__global__ __launch_bounds__(256) void cvt_f32_bf16(const float* __restrict__ in,
                                                    uint16_t* __restrict__ out, int n4) {
  int stride = gridDim.x * blockDim.x;
  for (int i = blockIdx.x * blockDim.x + threadIdx.x; i < n4; i += stride) {
    float4 v = ((const float4*)in)[i];
    ushort4 o;
    o.x = f2bf(v.x); o.y = f2bf(v.y); o.z = f2bf(v.z); o.w = f2bf(v.w);
    ((ushort4*)out)[i] = o;
  }
}

// all 4 weight matrices in one dispatch; out contiguous Wq|Wk|Wv|Wo
__global__ __launch_bounds__(256) void cvt_w4(const float* __restrict__ wq,
                                              const float* __restrict__ wk,
                                              const float* __restrict__ wv,
                                              const float* __restrict__ wo,
                                              uint16_t* __restrict__ out) {
  const int sel = blockIdx.y;
  const float* src = sel == 0 ? wq : sel == 1 ? wk : sel == 2 ? wv : wo;
  uint16_t* dst = out + (size_t)sel * DM * DM;
  const int n4 = DM * DM / 4;
  const int stride = gridDim.x * blockDim.x;
  for (int i = blockIdx.x * blockDim.x + threadIdx.x; i < n4; i += stride) {
    float4 v = ((const float4*)src)[i];
    ushort4 o;
    o.x = f2bf(v.x); o.y = f2bf(v.y); o.z = f2bf(v.z); o.w = f2bf(v.w);
    ((ushort4*)dst)[i] = o;
  }
}

// ---------------- 8-phase 256x256 GEMM: C[m][n] = sum_k A[m][k]*Bw[n][k] ------------
// BK=64, 512 threads = 8 waves (2M x 4N), wave tile 128x64 (8x4 frags).
// LDS: per {A,B} x {tile-parity} x {k32-chunk} slots of 256x32 bf16 (16 KB) =
// 128 KB. Slot rows are 64 B -> fragment ds_read_b128 is conflict-free with a
// LINEAR layout (no swizzle needed; gload_lds dest stays linear).
// Phase p (of 8/iter, 2 K-tiles/iter): t2=p>>2 (tile parity), kc=(p>>1)&1,
// mh=p&1 (wave-tile M-half). Per phase: vmcnt(6); ds_read 4xA (+4xB if mh==0);
// stage ONE 16KB half 5-6 phases ahead of its read; barrier; 16 MFMA under
// setprio(1); barrier. Ring: p0:A[1][1](t+1) p1:B[1][1](t+1) p2:A[0][0](t+2)
// p3:B[0][0](t+2) p4:A[0][1](t+2) p5:B[0][1](t+2) p6:A[1][0](t+3) p7:B[1][0](t+3)
// — every slot staged only after its last read, read only >=5 phases after
// staging (vmcnt(6)+end-barrier chain makes cross-wave landing visible).
// MODE 0: n in [0,3072); tsel=bn>>10 -> q/k/v; q,k RoPE'd in-epilogue (q also
//         pre-scaled by 0.125*log2e); bf16 scatter to [tsel][B,H,S,DH].
// MODE 1: fp32 [M][DM].
template<int MODE>
__global__ __launch_bounds__(512, 2) void gemm8p(const uint16_t* __restrict__ Aa,
                                                 const uint16_t* __restrict__ Bw,
                                                 void* __restrict__ outp,
                                                 const int* __restrict__ pos) {
  constexpr int K = DM;
  __shared__ __align__(16) uint16_t sA[2][2][256 * 32];
  __shared__ __align__(16) uint16_t sB[2][2][256 * 32];
  const int tid = threadIdx.x;
  const int w = tid >> 6, lane = tid & 63;
  const int l15 = lane & 15, lhi = lane >> 4;
  const int wr = w >> 2, wc = w & 3;  // 2M x 4N waves

  // XCD-aware block swizzle (grids are %8==0)
  const int nx = gridDim.x, nwg = nx * gridDim.y;
  const int flat = blockIdx.y * nx + blockIdx.x;
  const int wg = (flat & 7) * (nwg >> 3) + (flat >> 3);
  const int bm = (wg / nx) * 256, bn = (wg % nx) * 256;

  const int r0 = tid >> 2;            // staging: row within 128-row half
  const int c0 = (tid & 3) * 8;       // staging: elem offset within 32-elem k-chunk

  auto stageA = [&](int par, int kc, int tt) {
    const int kk = tt * 64 + kc * 32;
#pragma unroll
    for (int j = 0; j < 2; ++j)
      async_copy16((char*)sA + ((par * 2 + kc) * 1024 + j * 512 + tid) * 16,
                   (const char*)Aa + ((size_t)(bm + j * 128 + r0) * K + kk + c0) * 2);
  };
  auto stageB = [&](int par, int kc, int tt) {
    const int kk = tt * 64 + kc * 32;
#pragma unroll
    for (int j = 0; j < 2; ++j)
      async_copy16((char*)sB + ((par * 2 + kc) * 1024 + j * 512 + tid) * 16,
                   (const char*)Bw + ((size_t)(bn + j * 128 + r0) * K + kk + c0) * 2);
  };

  f32x4 acc[8][4] = {};

  // prologue: tile0 fully + tile1 kc0 halves (6 halves, 12 loads/thread)
  stageA(0, 0, 0); stageB(0, 0, 0);
  stageA(0, 1, 0); stageB(0, 1, 0);
  stageA(1, 0, 1); stageB(1, 0, 1);
  asm volatile("s_waitcnt vmcnt(6)" ::: "memory");
  __builtin_amdgcn_s_barrier();

  constexpr int NIT = K / 128;  // 8 iterations, 2 K-tiles each
  for (int it = 0; it < NIT; ++it) {
    const int base = 2 * it;
    bf16x8 bfr[4];
#pragma unroll
    for (int p = 0; p < 8; ++p) {
      const int t2 = p >> 2, kc = (p >> 1) & 1, mh = p & 1;

      asm volatile("s_waitcnt vmcnt(6)" ::: "memory");
      __builtin_amdgcn_sched_barrier(0);

      // fragment reads (conflict-free: 64 B rows)
      bf16x8 af[4];
      const char* slotA = (const char*)&sA[t2][kc][0];
#pragma unroll
      for (int mf = 0; mf < 4; ++mf)
        af[mf] = *(const bf16x8*)(slotA + (wr * 128 + mh * 64 + mf * 16 + l15) * 64 + lhi * 16);
      if (mh == 0) {
        const char* slotB = (const char*)&sB[t2][kc][0];
#pragma unroll
        for (int nf = 0; nf < 4; ++nf)
          bfr[nf] = *(const bf16x8*)(slotB + (wc * 64 + nf * 16 + l15) * 64 + lhi * 16);
      }

      // stage one half-tile per the ring schedule (clamped at the K tail)
      {
        int tt;
        switch (p) {
          case 0: tt = base + 1; if (tt > 15) tt = 15; stageA(1, 1, tt); break;
          case 1: tt = base + 1; if (tt > 15) tt = 15; stageB(1, 1, tt); break;
          case 2: tt = base + 2; if (tt > 15) tt = 15; stageA(0, 0, tt); break;
          case 3: tt = base + 2; if (tt > 15) tt = 15; stageB(0, 0, tt); break;
          case 4: tt = base + 2; if (tt > 15) tt = 15; stageA(0, 1, tt); break;
          case 5: tt = base + 2; if (tt > 15) tt = 15; stageB(0, 1, tt); break;
          case 6: tt = base + 3; if (tt > 15) tt = 15; stageA(1, 0, tt); break;
          default: tt = base + 3; if (tt > 15) tt = 15; stageB(1, 0, tt); break;
        }
      }

      __builtin_amdgcn_s_barrier();
      __builtin_amdgcn_s_setprio(1);
#pragma unroll
      for (int mf = 0; mf < 4; ++mf)
#pragma unroll
        for (int nf = 0; nf < 4; ++nf)
          acc[mh * 4 + mf][nf] = __builtin_amdgcn_mfma_f32_16x16x32_bf16(
              af[mf], bfr[nf], acc[mh * 4 + mf][nf], 0, 0, 0);
      __builtin_amdgcn_s_setprio(0);
      __builtin_amdgcn_s_barrier();
    }
  }

  if (MODE == 0) {
    const int tsel = bn >> 10;  // uniform per block (1024 % 256 == 0)
    uint16_t* out = (uint16_t*)outp + (size_t)tsel * ((size_t)MTOT * DM);
    if (tsel < 2) {
      // RoPE fused: lane pair (even d, odd d) exchanges via shfl_xor(.,1).
      const float l2t_32 = 0.41524101186092074f;            // log2(10000)/32
      const float qsc = tsel == 0 ? 0.18033688011112042f : 1.0f;  // 0.125*log2e
#pragma unroll
      for (int mfi = 0; mfi < 8; ++mfi) {
        const int mo = (mfi >> 2) * 64 + (mfi & 3) * 16;
        float ps[4];
#pragma unroll
        for (int r = 0; r < 4; ++r) {
          const int m = bm + wr * 128 + mo + lhi * 4 + r;
          ps[r] = (float)pos[m & (S_LEN - 1)];
        }
#pragma unroll
        for (int nf = 0; nf < 4; ++nf) {
          const int n = bn + wc * 64 + nf * 16 + l15;
          const int e = n & 1023;
          const int h = e >> 6, d = e & 63;
          const float inv = __builtin_amdgcn_exp2f(-(float)(d >> 1) * l2t_32);
#pragma unroll
          for (int r = 0; r < 4; ++r) {
            const int m = bm + wr * 128 + mo + lhi * 4 + r;
            const int b = m >> 11, s = m & (S_LEN - 1);
            const float v = acc[mfi][nf][r];
            const float pr = __shfl_xor(v, 1);
            const float ang = ps[r] * inv;
            const float cs = __cosf(ang) * qsc, sn = __sinf(ang) * qsc;
            const float val = (l15 & 1) ? (pr * sn + v * cs) : (v * cs - pr * sn);
            out[(((size_t)(b * NH + h) * S_LEN + s) << 6) + d] = f2bf(val);
          }
        }
      }
    } else {
#pragma unroll
      for (int mfi = 0; mfi < 8; ++mfi) {
        const int mo = (mfi >> 2) * 64 + (mfi & 3) * 16;
#pragma unroll
        for (int nf = 0; nf < 4; ++nf)
#pragma unroll
          for (int r = 0; r < 4; ++r) {
            const int m = bm + wr * 128 + mo + lhi * 4 + r;
            const int n = bn + wc * 64 + nf * 16 + l15;
            const int b = m >> 11, s = m & (S_LEN - 1);
            const int e = n & 1023;
            const int h = e >> 6, d = e & 63;
            out[(((size_t)(b * NH + h) * S_LEN + s) << 6) + d] = f2bf(acc[mfi][nf][r]);
          }
      }
    }
  } else {
    float* out = (float*)outp;  // [M][DM]
#pragma unroll
    for (int mfi = 0; mfi < 8; ++mfi) {
      const int mo = (mfi >> 2) * 64 + (mfi & 3) * 16;
#pragma unroll
      for (int nf = 0; nf < 4; ++nf)
#pragma unroll
        for (int r = 0; r < 4; ++r) {
          const int m = bm + wr * 128 + mo + lhi * 4 + r;
          const int n = bn + wc * 64 + nf * 16 + l15;
          out[(size_t)m * DM + n] = acc[mfi][nf][r];
        }
    }
  }
}

// ---------------- V transpose: [BH][S][64] -> [BH][64][S], sigma-permuted ------------
__global__ __launch_bounds__(256) void transpose_v(const uint16_t* __restrict__ v,
                                                   uint16_t* __restrict__ vt) {
  __shared__ uint16_t t[64 * 65];
  const int bh = blockIdx.y, s0 = blockIdx.x * 64;
  const uint16_t* vb = v + (size_t)bh * S_LEN * 64 + (size_t)s0 * 64;
  uint16_t* ob = vt + (size_t)bh * 64 * S_LEN + s0;
  for (int o = threadIdx.x; o < 64 * 64; o += 256) {
    const int r = o >> 6, c = o & 63;
    t[c * 65 + r] = vb[(size_t)r * 64 + c];
  }
  __syncthreads();
  for (int o = threadIdx.x; o < 64 * 64; o += 256) {
    const int d = o >> 6, p = o & 63;
    const int sp = (p & 32) | (((p >> 2) & 3) << 3) | (((p >> 4) & 1) << 2) | (p & 3);
    ob[(size_t)d * S_LEN + sp] = t[d * 65 + p];
  }
}

// ---------------- causal flash attention (swapped QK^T, in-register P) ---------------
__global__ __launch_bounds__(512, 4) void attn_kernel(const uint16_t* __restrict__ q,
                                                      const uint16_t* __restrict__ kk,
                                                      const uint16_t* __restrict__ vt,
                                                      uint16_t* __restrict__ o) {
  const int bh = blockIdx.y;
  const int p = blockIdx.x;  // pair id: handles qtiles {15-p, p}
  const int tid = threadIdx.x;
  const int w = __builtin_amdgcn_readfirstlane(tid >> 6);
  const int lane = tid & 63;
  const int l15 = lane & 15, lhi = lane >> 4;
  const uint16_t* qb = q + (size_t)bh * S_LEN * DH;
  const uint16_t* kb = kk + (size_t)bh * S_LEN * DH;
  const uint16_t* vb = vt + (size_t)bh * DH * S_LEN;

  __shared__ uint16_t lK[2][128 * 64];  // [kv 128][d 64], 128B rows
  __shared__ uint16_t lV[2][64 * 128];  // [d 64][kv 128], 256B rows

  const int krow_l = lane >> 3;
  const int scK = (lane & 7) ^ krow_l;
  const int vrow_l = lane >> 4;

  auto stage = [&](int b, int t) {
    const int k0 = t * 128;
#pragma unroll
    for (int i = 0; i < 2; ++i) {
      const int krow = w * 16 + i * 8 + krow_l;
      async_copy16((char*)lK[b] + w * 2048 + i * 1024 + lane * 16,
                   (const char*)kb + ((size_t)(k0 + krow) * 64 + scK * 8) * 2);
      const int vd = w * 8 + i * 4 + vrow_l;
      const int scV = (lane & 15) ^ (vd & 15);
      async_copy16((char*)lV[b] + w * 2048 + i * 1024 + lane * 16,
                   (const char*)vb + ((size_t)vd * S_LEN + k0 + scV * 8) * 2);
    }
  };

  stage(0, 0);
  asm volatile("s_waitcnt vmcnt(0)" ::: "memory");
  __syncthreads();

  int cur = 0;
  const int b_out = bh >> 4, h_out = bh & 15;

  for (int s = 0; s < 2; ++s) {
    const int qtile = s ? p : (15 - p);
    const int q0 = qtile * 128 + w * 16;

    bf16x8 qf[2];
#pragma unroll
    for (int c = 0; c < 2; ++c)
      qf[c] = *(const bf16x8*)(qb + (size_t)(q0 + l15) * DH + c * 32 + lhi * 8);

    f32x4 oa[4] = {};
    float mr = -1e30f, lr = 0.f;

    const int nt = qtile + 1;
    for (int t = 0; t < nt; ++t) {
      if (t + 1 < nt) stage(cur ^ 1, t + 1);
      else if (s == 0) stage(cur ^ 1, 0);

      const bool diag = (t == qtile);
      const int fMf = diag ? w : 7;
      const int fE  = diag ? (w | 1) : 7;
      const int cE  = diag ? (w >> 1) : 3;

      f32x4 sf[8];
      __builtin_amdgcn_s_setprio(1);
#pragma unroll
      for (int f = 0; f < 8; ++f) {
        f32x4 z = {0.f, 0.f, 0.f, 0.f};
        if (f <= fMf) {
          const int kr = f * 16 + l15;
          const char* kbase = (const char*)lK[cur] + kr * 128;
          bf16x8 kf0 = *(const bf16x8*)(kbase + ((lhi ^ (kr & 7)) << 4));
          bf16x8 kf1 = *(const bf16x8*)(kbase + (((4 + lhi) ^ (kr & 7)) << 4));
          z = __builtin_amdgcn_mfma_f32_16x16x32_bf16(kf0, qf[0], z, 0, 0, 0);
          z = __builtin_amdgcn_mfma_f32_16x16x32_bf16(kf1, qf[1], z, 0, 0, 0);
        }
        sf[f] = z;
      }
      __builtin_amdgcn_s_setprio(0);

      if (diag) {
        const int qrow = q0 + l15;
        const int k0 = t * 128;
#pragma unroll
        for (int f = 0; f < 8; ++f)
          if (f <= fE)
#pragma unroll
            for (int r = 0; r < 4; ++r) {
              const int kv = k0 + f * 16 + lhi * 4 + r;
              if (kv > qrow) sf[f][r] = -1e30f;
            }
      }

      float pm = -1e30f;
#pragma unroll
      for (int f = 0; f < 8; ++f)
        if (f <= fE)
#pragma unroll
          for (int r = 0; r < 4; ++r) pm = fmaxf(pm, sf[f][r]);
      pm = fmaxf(pm, __shfl_xor(pm, 16));
      pm = fmaxf(pm, __shfl_xor(pm, 32));

      if (!__all(pm <= mr + 8.0f)) {
        const float mn = fmaxf(mr, pm);
        const float resc = __builtin_amdgcn_exp2f(mr - mn);
        mr = mn;
        lr *= resc;
#pragma unroll
        for (int r = 0; r < 4; ++r) {
          const float rb = __shfl(resc, (lhi << 2) + r);
#pragma unroll
          for (int df = 0; df < 4; ++df) oa[df][r] *= rb;
        }
      }

      float rs = 0.f;
#pragma unroll
      for (int f = 0; f < 8; ++f)
        if (f <= fE)
#pragma unroll
          for (int r = 0; r < 4; ++r) {
            const float pv = __builtin_amdgcn_exp2f(sf[f][r] - mr);
            sf[f][r] = pv;
            rs += pv;
          }
      rs += __shfl_xor(rs, 16);
      rs += __shfl_xor(rs, 32);
      lr += rs;

#pragma unroll
      for (int c = 0; c < 4; ++c) {
        if (c <= cE) {
          u32x4 u;
          u.x = cvt_pk_bf16(sf[2 * c][0], sf[2 * c][1]);
          u.y = cvt_pk_bf16(sf[2 * c][2], sf[2 * c][3]);
          u.z = cvt_pk_bf16(sf[2 * c + 1][0], sf[2 * c + 1][1]);
          u.w = cvt_pk_bf16(sf[2 * c + 1][2], sf[2 * c + 1][3]);
          bf16x8 pa = __builtin_bit_cast(bf16x8, u);
          __builtin_amdgcn_s_setprio(1);
#pragma unroll
          for (int df = 0; df < 4; ++df) {
            const int vr = df * 16 + l15;
            bf16x8 vf = *(const bf16x8*)((const char*)lV[cur] + vr * 256 +
                                         ((((c << 2) + lhi) ^ (vr & 15)) << 4));
            oa[df] = __builtin_amdgcn_mfma_f32_16x16x32_bf16(pa, vf, oa[df], 0, 0, 0);
          }
          __builtin_amdgcn_s_setprio(0);
        }
      }

      asm volatile("s_waitcnt vmcnt(0)" ::: "memory");
      __syncthreads();
      cur ^= 1;
    }

    float inv[4];
#pragma unroll
    for (int r = 0; r < 4; ++r)
      inv[r] = __builtin_amdgcn_rcpf(__shfl(lr, (lhi << 2) + r));
#pragma unroll
    for (int df = 0; df < 4; ++df)
#pragma unroll
      for (int r = 0; r < 4; ++r) {
        const int srow_o = q0 + lhi * 4 + r;
        const float val = oa[df][r] * inv[r];
        const int d = df * 16 + l15;
        o[((size_t)(b_out * S_LEN + srow_o)) * DM + h_out * 64 + d] = f2bf(val);
      }
  }
}

extern "C" void kernel_launch(void* const* d_in, const int* in_sizes, int n_in,
                              void* d_out, int out_size, void* d_ws, size_t ws_size,
                              hipStream_t stream) {
  const float* x = (const float*)d_in[0];
  const float* Wq = (const float*)d_in[1];
  const float* Wk = (const float*)d_in[2];
  const float* Wv = (const float*)d_in[3];
  const float* Wo = (const float*)d_in[4];
  const int* pos = (const int*)d_in[5];

  char* ws = (char*)d_ws;
  size_t off = 0;
  auto alloc = [&](size_t bytes) {
    void* p = ws + off;
    off += (bytes + 255) & ~(size_t)255;
    return p;
  };
  uint16_t* xb    = (uint16_t*)alloc((size_t)MTOT * DM * 2);      // also reused as attn output
  uint16_t* wqkvb = (uint16_t*)alloc((size_t)4 * DM * DM * 2);    // contiguous Wq|Wk|Wv|Wo
  uint16_t* qkvb  = (uint16_t*)alloc((size_t)3 * MTOT * DM * 2);  // contiguous q|k|v
  uint16_t* vtb   = (uint16_t*)alloc((size_t)MTOT * DM * 2);      // v, transposed+sigma
  uint16_t* wob = wqkvb + (size_t)3 * DM * DM;
  uint16_t* qb = qkvb;
  uint16_t* kbuf = qkvb + (size_t)MTOT * DM;
  uint16_t* vbuf = qkvb + (size_t)2 * MTOT * DM;
  uint16_t* attnb = xb;  // reuse: x (bf16) dead after QKV projection

  cvt_f32_bf16<<<2048, 256, 0, stream>>>(x, xb, MTOT * DM / 4);
  cvt_w4<<<dim3(128, 4), 256, 0, stream>>>(Wq, Wk, Wv, Wo, wqkvb);

  // fused QKV projection + RoPE: 256x256 tiles, 8-phase schedule
  gemm8p<0><<<dim3(12, MTOT / 256), 512, 0, stream>>>(xb, wqkvb, qkvb, pos);

  transpose_v<<<dim3(32, 64), 256, 0, stream>>>(vbuf, vtb);

  attn_kernel<<<dim3(8, 64), 512, 0, stream>>>(qb, kbuf, vtb, attnb);

  // output projection: 256x256 tiles, 8-phase schedule
  gemm8p<1><<<dim3(4, MTOT / 256), 512, 0, stream>>>(attnb, wob, d_out, nullptr);
}